// Round 1
// baseline (220.472 us; speedup 1.0000x reference)
//
#include <hip/hip_runtime.h>

// Problem constants (fixed by setup_inputs): B=32, C=256, H=W=64
#define BATCH 32
#define CHAN  256
#define HGT   64
#define WID   64
#define HW    4096            // HGT*WID
#define BPB   16              // blocks per batch
#define CPB   (CHAN / BPB)    // 16 channels per block

// Fully fused: each block rebuilds its batch's scatter-accumulated bilinear
// weight map in LDS (redundant x16 per batch -- cheap, offset is L2-resident),
// then streams CPB channel planes and dots them against the map.
// No workspace (d_ws unused), single launch.
__global__ __launch_bounds__(256, 2) void fused_bilinear_pool(
        const float* __restrict__ data,     // [B, C, H, W] fp32
        const float* __restrict__ offset,   // [B, 2, H, W] fp32
        const float* __restrict__ ts_ptr,   // scalar fp32
        float* __restrict__ out)            // [B, C] fp32
{
    const int blk = blockIdx.x;
    const int b   = blk >> 4;               // blk / BPB
    const int c0  = (blk & (BPB - 1)) * CPB;
    const int tid = threadIdx.x;

    __shared__ float acc[HW];               // 16 KiB weight map
    __shared__ float wred[4][CPB];          // cross-wave reduce scratch

    #pragma unroll
    for (int it = 0; it < 16; ++it) acc[it * 256 + tid] = 0.0f;
    __syncthreads();

    float ts = ts_ptr[0];
    ts = fminf(fmaxf(ts, 0.001f), 0.01f);

    const float* off_y = offset + (size_t)b * 2 * HW;   // offset[b,0]
    const float* off_x = off_y + HW;                    // offset[b,1]

    // ---- Phase A: scatter bilinear weights into acc (LDS float atomics) ----
    // 4 points per thread per iter via float4 loads (W=64 so all 4 share a row).
    #pragma unroll
    for (int it = 0; it < 4; ++it) {
        const int p4 = (it * 256 + tid) * 4;
        const float4 dy4 = *reinterpret_cast<const float4*>(off_y + p4);
        const float4 dx4 = *reinterpret_cast<const float4*>(off_x + p4);
        const int i  = p4 >> 6;
        const int j0 = p4 & 63;
        const float dys[4] = {dy4.x, dy4.y, dy4.z, dy4.w};
        const float dxs[4] = {dx4.x, dx4.y, dx4.z, dx4.w};
        #pragma unroll
        for (int e = 0; e < 4; ++e) {
            // reference eval order: clip(i + ts*dy*H, 0, H-1)
            float y = fminf(fmaxf((float)i + ts * dys[e] * 64.0f, 0.0f), 63.0f);
            float x = fminf(fmaxf((float)(j0 + e) + ts * dxs[e] * 64.0f, 0.0f), 63.0f);
            int y0 = (int)floorf(y); y0 = min(max(y0, 0), HGT - 2);
            int x0 = (int)floorf(x); x0 = min(max(x0, 0), WID - 2);
            const float wy = y - (float)y0;
            const float wx = x - (float)x0;
            const int base = (y0 << 6) + x0;
            atomicAdd(&acc[base],           (1.0f - wy) * (1.0f - wx));
            atomicAdd(&acc[base + 1],       (1.0f - wy) * wx);
            atomicAdd(&acc[base + WID],     wy * (1.0f - wx));
            atomicAdd(&acc[base + WID + 1], wy * wx);
        }
    }
    __syncthreads();

    // ---- Phase B: stream CPB channel planes, dot against acc ----
    // Per it: 1 LDS float4 of acc + 16 independent global float4 loads in
    // flight (one per channel). sums[] is fully statically indexed (no scratch).
    float sums[CPB];
    #pragma unroll
    for (int ci = 0; ci < CPB; ++ci) sums[ci] = 0.0f;

    const float* plane0 = data + ((size_t)b * CHAN + c0) * HW;

    #pragma unroll
    for (int it = 0; it < 4; ++it) {
        const int idx = (it * 256 + tid) * 4;
        const float4 av = *reinterpret_cast<const float4*>(acc + idx);
        #pragma unroll
        for (int ci = 0; ci < CPB; ++ci) {
            const float4 dv =
                *reinterpret_cast<const float4*>(plane0 + (size_t)ci * HW + idx);
            sums[ci] = fmaf(av.x, dv.x, sums[ci]);
            sums[ci] = fmaf(av.y, dv.y, sums[ci]);
            sums[ci] = fmaf(av.z, dv.z, sums[ci]);
            sums[ci] = fmaf(av.w, dv.w, sums[ci]);
        }
    }

    // ---- Phase C: one deferred reduction for all CPB channels ----
    const int lane = tid & 63;
    const int wv   = tid >> 6;
    #pragma unroll
    for (int ci = 0; ci < CPB; ++ci) {
        float v = sums[ci];
        #pragma unroll
        for (int off = 32; off > 0; off >>= 1)
            v += __shfl_down(v, off, 64);
        if (lane == 0) wred[wv][ci] = v;
    }
    __syncthreads();

    if (tid < CPB) {
        const float r = wred[0][tid] + wred[1][tid] + wred[2][tid] + wred[3][tid];
        out[(b << 8) + c0 + tid] = r * (1.0f / (float)HW);   // fold the mean
    }
}

extern "C" void kernel_launch(void* const* d_in, const int* in_sizes, int n_in,
                              void* d_out, int out_size, void* d_ws, size_t ws_size,
                              hipStream_t stream) {
    const float* data   = (const float*)d_in[0];  // fp32 [32,256,64,64]
    const float* offset = (const float*)d_in[1];  // fp32 [32,2,64,64]
    const float* ts     = (const float*)d_in[2];  // fp32 scalar

    float* out = (float*)d_out;                   // [32, 256] fp32
    (void)d_ws; (void)ws_size;                    // workspace intentionally unused

    fused_bilinear_pool<<<BATCH * BPB, 256, 0, stream>>>(data, offset, ts, out);
}

// Round 3
// 219.582 us; speedup vs baseline: 1.0040x; 1.0040x over previous
//
#include <hip/hip_runtime.h>

// Problem constants (fixed by setup_inputs): B=32, C=256, H=W=64
#define BATCH 32
#define CHAN  256
#define HGT   64
#define WID   64
#define HW    4096   // HGT*WID

// native clang vector type (required by __builtin_nontemporal_load)
typedef float v4f __attribute__((ext_vector_type(4)));

// Kernel 1: build per-batch scatter-accumulated bilinear weight map A[b, 0:4096].
// One block per batch. Stride-256 p-loop keeps LDS atomic conflicts ~2-way.
// Mean (1/4096) is folded into the map.
__global__ __launch_bounds__(256) void weight_map_kernel(
        const float* __restrict__ offset,   // [B, 2, H, W] fp32
        const float* __restrict__ ts_ptr,   // scalar fp32
        float* __restrict__ A)              // [B, 4096] fp32 (d_ws)
{
    const int b   = blockIdx.x;
    const int tid = threadIdx.x;

    __shared__ float acc[HW];   // 16 KiB
    for (int k = tid; k < HW; k += 256) acc[k] = 0.0f;
    __syncthreads();

    float ts = ts_ptr[0];
    ts = fminf(fmaxf(ts, 0.001f), 0.01f);

    const float* off_y = offset + (size_t)b * 2 * HW;   // offset[b,0]
    const float* off_x = off_y + HW;                    // offset[b,1]

    #pragma unroll 4
    for (int p = tid; p < HW; p += 256) {
        const int i = p >> 6;
        const int j = p & 63;
        const float dy = off_y[p];
        const float dx = off_x[p];
        // reference eval order: clip(i + (ts*offset)*H, 0, H-1)
        float y = fminf(fmaxf((float)i + ts * dy * 64.0f, 0.0f), 63.0f);
        float x = fminf(fmaxf((float)j + ts * dx * 64.0f, 0.0f), 63.0f);
        int y0 = (int)floorf(y); y0 = min(max(y0, 0), HGT - 2);
        int x0 = (int)floorf(x); x0 = min(max(x0, 0), WID - 2);
        const float wy = y - (float)y0;
        const float wx = x - (float)x0;
        const int base = (y0 << 6) + x0;
        atomicAdd(&acc[base],           (1.0f - wy) * (1.0f - wx));
        atomicAdd(&acc[base + 1],       (1.0f - wy) * wx);
        atomicAdd(&acc[base + WID],     wy * (1.0f - wx));
        atomicAdd(&acc[base + WID + 1], wy * wx);
    }
    __syncthreads();

    float* Ab = A + (size_t)b * HW;
    const float s = 1.0f / (float)HW;   // fold the mean into the weight map
    for (int k = tid; k < HW; k += 256) Ab[k] = acc[k] * s;
}

// Kernel 2: O[b,c] = dot(A[b,:], data[b,c,:]).
// ONE WAVE per (b,c) plane: no __syncthreads, no LDS, register-only shuffle
// reduce. Per burst: 4 nontemporal data float4 + 4 A float4 = 8 independent
// loads in flight (128 B/lane). VGPR capped <=64 via launch_bounds(256,8)
// so all 32 waves/CU are resident. NT hint on data keeps A[b] cache-resident.
__global__ __launch_bounds__(256, 8) void dot_kernel(
        const float* __restrict__ data,   // [B, C, H, W] fp32
        const float* __restrict__ A,      // [B, 4096] fp32
        float* __restrict__ out)          // [B, C] fp32
{
    const int wave = (blockIdx.x << 2) + (threadIdx.x >> 6);  // 0..8191 = b*CHAN+c
    const int lane = threadIdx.x & 63;
    const int b    = wave >> 8;

    const float* plane = data + (size_t)wave * HW;
    const float* Ab    = A    + (size_t)b    * HW;

    float sum = 0.0f;
    #pragma unroll
    for (int it = 0; it < 4; ++it) {
        // wave covers 4 contiguous 1 KiB segments per iteration
        const int i0 = ((it * 4 + 0) * 64 + lane) * 4;
        const int i1 = ((it * 4 + 1) * 64 + lane) * 4;
        const int i2 = ((it * 4 + 2) * 64 + lane) * 4;
        const int i3 = ((it * 4 + 3) * 64 + lane) * 4;

        const v4f d0 = __builtin_nontemporal_load(
                           reinterpret_cast<const v4f*>(plane + i0));
        const v4f d1 = __builtin_nontemporal_load(
                           reinterpret_cast<const v4f*>(plane + i1));
        const v4f d2 = __builtin_nontemporal_load(
                           reinterpret_cast<const v4f*>(plane + i2));
        const v4f d3 = __builtin_nontemporal_load(
                           reinterpret_cast<const v4f*>(plane + i3));
        const v4f a0 = *reinterpret_cast<const v4f*>(Ab + i0);
        const v4f a1 = *reinterpret_cast<const v4f*>(Ab + i1);
        const v4f a2 = *reinterpret_cast<const v4f*>(Ab + i2);
        const v4f a3 = *reinterpret_cast<const v4f*>(Ab + i3);

        sum = fmaf(a0.x, d0.x, sum); sum = fmaf(a0.y, d0.y, sum);
        sum = fmaf(a0.z, d0.z, sum); sum = fmaf(a0.w, d0.w, sum);
        sum = fmaf(a1.x, d1.x, sum); sum = fmaf(a1.y, d1.y, sum);
        sum = fmaf(a1.z, d1.z, sum); sum = fmaf(a1.w, d1.w, sum);
        sum = fmaf(a2.x, d2.x, sum); sum = fmaf(a2.y, d2.y, sum);
        sum = fmaf(a2.z, d2.z, sum); sum = fmaf(a2.w, d2.w, sum);
        sum = fmaf(a3.x, d3.x, sum); sum = fmaf(a3.y, d3.y, sum);
        sum = fmaf(a3.z, d3.z, sum); sum = fmaf(a3.w, d3.w, sum);
    }

    // wave-64 register-only shuffle reduce; no LDS, no barrier
    #pragma unroll
    for (int off = 32; off > 0; off >>= 1)
        sum += __shfl_down(sum, off, 64);

    if (lane == 0) out[wave] = sum;
}

extern "C" void kernel_launch(void* const* d_in, const int* in_sizes, int n_in,
                              void* d_out, int out_size, void* d_ws, size_t ws_size,
                              hipStream_t stream) {
    const float* data   = (const float*)d_in[0];  // fp32 [32,256,64,64]
    const float* offset = (const float*)d_in[1];  // fp32 [32,2,64,64]
    const float* ts     = (const float*)d_in[2];  // fp32 scalar

    float* A   = (float*)d_ws;   // [32, 4096] fp32 = 512 KiB scratch
    float* out = (float*)d_out;  // [32, 256] fp32

    weight_map_kernel<<<BATCH, 256, 0, stream>>>(offset, ts, A);
    // one wave per (b,c) plane -> 8192 waves = 2048 blocks of 4 waves
    dot_kernel<<<(BATCH * CHAN) / 4, 256, 0, stream>>>(data, A, out);
}

// Round 4
// 210.565 us; speedup vs baseline: 1.0470x; 1.0428x over previous
//
#include <hip/hip_runtime.h>

// Problem constants (fixed by setup_inputs): B=32, C=256, H=W=64
#define BATCH 32
#define CHAN  256
#define HGT   64
#define WID   64
#define HW    4096   // HGT*WID

// Kernel 1: build per-batch scatter-accumulated bilinear weight map A[b, 0:4096].
// One block per batch, 1024 threads (4 waves x 4 -> 4x the parallelism of the
// 256-thread version; only 32 blocks so per-block speed matters).
// Stride-1024 p-loop keeps col == lane -> 2-way LDS bank aliasing (free).
// Mean (1/4096) is folded into the map.
__global__ __launch_bounds__(1024) void weight_map_kernel(
        const float* __restrict__ offset,   // [B, 2, H, W] fp32
        const float* __restrict__ ts_ptr,   // scalar fp32
        float* __restrict__ A)              // [B, 4096] fp32 (d_ws)
{
    const int b   = blockIdx.x;
    const int tid = threadIdx.x;

    __shared__ float acc[HW];   // 16 KiB
    acc[tid]        = 0.0f;
    acc[tid + 1024] = 0.0f;
    acc[tid + 2048] = 0.0f;
    acc[tid + 3072] = 0.0f;
    __syncthreads();

    float ts = ts_ptr[0];
    ts = fminf(fmaxf(ts, 0.001f), 0.01f);

    const float* off_y = offset + (size_t)b * 2 * HW;   // offset[b,0]
    const float* off_x = off_y + HW;                    // offset[b,1]

    #pragma unroll
    for (int it = 0; it < 4; ++it) {
        const int p = tid + it * 1024;
        const int i = p >> 6;
        const int j = p & 63;
        const float dy = off_y[p];
        const float dx = off_x[p];
        // reference eval order: clip(i + (ts*offset)*H, 0, H-1)
        float y = fminf(fmaxf((float)i + ts * dy * 64.0f, 0.0f), 63.0f);
        float x = fminf(fmaxf((float)j + ts * dx * 64.0f, 0.0f), 63.0f);
        int y0 = (int)floorf(y); y0 = min(max(y0, 0), HGT - 2);
        int x0 = (int)floorf(x); x0 = min(max(x0, 0), WID - 2);
        const float wy = y - (float)y0;
        const float wx = x - (float)x0;
        const int base = (y0 << 6) + x0;
        atomicAdd(&acc[base],           (1.0f - wy) * (1.0f - wx));
        atomicAdd(&acc[base + 1],       (1.0f - wy) * wx);
        atomicAdd(&acc[base + WID],     wy * (1.0f - wx));
        atomicAdd(&acc[base + WID + 1], wy * wx);
    }
    __syncthreads();

    float* Ab = A + (size_t)b * HW;
    const float s = 1.0f / (float)HW;   // fold the mean into the weight map
    Ab[tid]        = acc[tid]        * s;
    Ab[tid + 1024] = acc[tid + 1024] * s;
    Ab[tid + 2048] = acc[tid + 2048] * s;
    Ab[tid + 3072] = acc[tid + 3072] * s;
}

// Kernel 2: O[b,c] = dot(A[b,:], data[b,c,:]) for TWO channels per block.
// Round-0 proven structure (block-level 256-thread tiles, plain allocating
// float4 loads so the L3-resident half of `data` keeps hitting), but each
// A float4 now feeds two planes: A L2 traffic and the reduce/barrier
// epilogue per byte of data are both halved.
__global__ __launch_bounds__(256) void dot_kernel(
        const float* __restrict__ data,   // [B, C, H, W] fp32
        const float* __restrict__ A,      // [B, 4096] fp32
        float* __restrict__ out)          // [B, C] fp32
{
    const int blk   = blockIdx.x;           // 0 .. B*CHAN/2 - 1
    const int b     = blk >> 7;
    const int cpair = (blk & 127) << 1;
    const int tid   = threadIdx.x;

    const float* plane0 = data + ((size_t)b * CHAN + cpair) * HW;
    const float* plane1 = plane0 + HW;
    const float* Ab     = A + (size_t)b * HW;

    float s0 = 0.0f, s1 = 0.0f;
    #pragma unroll
    for (int it = 0; it < 4; ++it) {
        const int idx = (it * 256 + tid) * 4;     // 4 fp32 / thread / iter
        const float4 av = *reinterpret_cast<const float4*>(Ab + idx);
        const float4 d0 = *reinterpret_cast<const float4*>(plane0 + idx);
        const float4 d1 = *reinterpret_cast<const float4*>(plane1 + idx);
        s0 = fmaf(av.x, d0.x, s0); s0 = fmaf(av.y, d0.y, s0);
        s0 = fmaf(av.z, d0.z, s0); s0 = fmaf(av.w, d0.w, s0);
        s1 = fmaf(av.x, d1.x, s1); s1 = fmaf(av.y, d1.y, s1);
        s1 = fmaf(av.z, d1.z, s1); s1 = fmaf(av.w, d1.w, s1);
    }

    // wave-64 shuffle reduce, two independent chains (they pipeline)
    #pragma unroll
    for (int off = 32; off > 0; off >>= 1) {
        s0 += __shfl_down(s0, off, 64);
        s1 += __shfl_down(s1, off, 64);
    }

    __shared__ float wsum[4][2];
    const int lane = tid & 63;
    const int wv   = tid >> 6;
    if (lane == 0) { wsum[wv][0] = s0; wsum[wv][1] = s1; }
    __syncthreads();
    if (tid < 2) {
        out[(b << 8) + cpair + tid] =
            wsum[0][tid] + wsum[1][tid] + wsum[2][tid] + wsum[3][tid];
    }
}

extern "C" void kernel_launch(void* const* d_in, const int* in_sizes, int n_in,
                              void* d_out, int out_size, void* d_ws, size_t ws_size,
                              hipStream_t stream) {
    const float* data   = (const float*)d_in[0];  // fp32 [32,256,64,64]
    const float* offset = (const float*)d_in[1];  // fp32 [32,2,64,64]
    const float* ts     = (const float*)d_in[2];  // fp32 scalar

    float* A   = (float*)d_ws;   // [32, 4096] fp32 = 512 KiB scratch
    float* out = (float*)d_out;  // [32, 256] fp32

    weight_map_kernel<<<BATCH, 1024, 0, stream>>>(offset, ts, A);
    // two (b,c) planes per block -> 4096 blocks
    dot_kernel<<<(BATCH * CHAN) / 2, 256, 0, stream>>>(data, A, out);
}